// Round 4
// baseline (230.899 us; speedup 1.0000x reference)
//
#include <hip/hip_runtime.h>

// LIF forward: X [B, T, N] fp32 -> spikes [B, T, N] fp32
// B=128, T=32, N=8192.
//   mem = (mem + x)/2 ; spike = (mem-1 > 0) ; mem = spike ? 0 : mem
// Memory-bound: ~206 MB effective HBM traffic -> ~34 us floor at 6.3 TB/s.
// R1: float4 naive, VGPR=24, 85.5 us, 2.55 TB/s (latency-bound, 2 loads in flight).
// R2: explicit double-buffer -> compiler collapsed it (VGPR 32), neutral 83.5 us.
// R3: float2, 8192 waves (full occupancy) -> ~72 us, ~2.9 TB/s. Still short:
//     loads and stores interleave in the scan chain; vmcnt retires IN ORDER,
//     so consuming x(t) transitively waits on store acks, and only ~1 load
//     per wave is ever in flight.
// R4: batch phases: 32 loads -> sched_barrier -> compute -> stores.
//     sched_barrier(0) stops the scheduler from sinking loads to uses
//     (the R2 failure). 32 outstanding 512B loads/wave = 16 KB/wave in
//     flight; stores never enter the load wait chain (in-order retirement:
//     vmcnt<=31-k drains loads only). VGPR ~80 -> 6 waves/SIMD, plus
//     grid oversubscription (8 blocks/CU geometric vs ~6 resident) keeps
//     fresh waves arriving like the 6.3 TB/s copy ubench.

#define T_STEPS 32
#define N2 4096           // N/2, compile-time so idx math is shifts
#define TN2 (T_STEPS * N2)

__global__ __launch_bounds__(256, 4) void lif_fwd_kernel(
    const float2* __restrict__ X, float2* __restrict__ out)
{
    const int idx = blockIdx.x * blockDim.x + threadIdx.x;  // over B * N2
    const int b = idx >> 12;          // / N2
    const int n = idx & (N2 - 1);
    const size_t base = (size_t)b * (size_t)TN2 + (size_t)n;

    const float2* __restrict__ px = X + base;
    float2* __restrict__ po = out + base;

    // ---- Phase A: issue ALL timestep loads (independent addresses) ----
    float2 x[T_STEPS];
#pragma unroll
    for (int t = 0; t < T_STEPS; ++t)
        x[t] = px[(size_t)t * (size_t)N2];

    // Pin the phase boundary: nothing moves across (prevents the compiler
    // from sinking loads down to their uses and collapsing MLP to 1).
    __builtin_amdgcn_sched_barrier(0);

    // ---- Phase B: the serial scan, registers only ----
    float m0 = 0.f, m1 = 0.f;
#pragma unroll
    for (int t = 0; t < T_STEPS; ++t) {
        // exact reference order: mem += (x - mem) * 0.5 ; threshold 1.0
        m0 = m0 + (x[t].x - m0) * 0.5f;
        m1 = m1 + (x[t].y - m1) * 0.5f;

        float2 s;
        s.x = (m0 - 1.0f > 0.0f) ? 1.0f : 0.0f;
        s.y = (m1 - 1.0f > 0.0f) ? 1.0f : 0.0f;

        m0 = (s.x != 0.0f) ? 0.0f : m0;
        m1 = (s.y != 0.0f) ? 0.0f : m1;

        x[t] = s;   // reuse the load registers for the result
    }

    __builtin_amdgcn_sched_barrier(0);

    // ---- Phase C: stores (never waited on inside the kernel) ----
#pragma unroll
    for (int t = 0; t < T_STEPS; ++t)
        po[(size_t)t * (size_t)N2] = x[t];
}

extern "C" void kernel_launch(void* const* d_in, const int* in_sizes, int n_in,
                              void* d_out, int out_size, void* d_ws, size_t ws_size,
                              hipStream_t stream) {
    const float2* X = (const float2*)d_in[0];
    float2* out = (float2*)d_out;

    const int total = in_sizes[0];          // B*T*N = 33554432
    const int threads = total / (2 * T_STEPS) * 1;  // B*N2
    const int B = total / (T_STEPS * 8192); // 128
    const int nthreads = B * N2;            // 524288

    const int block = 256;
    const int grid = (nthreads + block - 1) / block;  // 2048
    (void)threads;

    lif_fwd_kernel<<<grid, block, 0, stream>>>(X, out);
}

// Round 5
// 224.214 us; speedup vs baseline: 1.0298x; 1.0298x over previous
//
#include <hip/hip_runtime.h>

// LIF forward: X [B, T, N] fp32 -> spikes [B, T, N] fp32
// B=128, T=32, N=8192.
//   mem = mem + (x - mem)/2 ; spike = (mem-1 > 0) ; mem = spike ? 0 : mem
// Memory-bound: ~200 MB effective HBM traffic -> ~32 us floor at 6.3 TB/s.
// R1: float4 naive, VGPR=24, 85.5 us, 2.55 TB/s (loads sunk to uses).
// R2: double-buffer -> compiler collapsed (VGPR 32), neutral.
// R3: float2 full-occupancy TLP -> ~72 us, 2.9 TB/s. TLP insufficient.
// R4: phased loads + sched_barrier -> VGPR=36: loads sunk AGAIN at IR level;
//     sched_barrier only pins the MIR scheduler. 81.5 us.
// R5: asm volatile load burst. IR passes cannot sink volatile asm. 32
//     global_load_dwordx2 issue back-to-back (16 KB/wave in flight), one
//     s_waitcnt vmcnt(0), then empty "+v" volatile asms re-tie the values
//     so compute can't be hoisted above the wait. Stores issue after all
//     loads retired -> never in a wait chain (fillBuffer proves stores
//     alone do 6.7 TB/s at 9% occupancy).

#define T_STEPS 32
#define N2 4096           // N/2, compile-time so idx math is shifts
#define TN2 (T_STEPS * N2)

__global__ __launch_bounds__(256) void lif_fwd_kernel(
    const float2* __restrict__ X, float2* __restrict__ out)
{
    const int idx = blockIdx.x * blockDim.x + threadIdx.x;  // over B * N2
    const int b = idx >> 12;          // / N2
    const int n = idx & (N2 - 1);
    const size_t base = (size_t)b * (size_t)TN2 + (size_t)n;

    const float2* p = X + base;
    float2* __restrict__ po = out + base;

    // ---- Phase A: force-issue ALL 32 timestep loads (volatile asm cannot
    // be sunk by any compiler pass). 64 data VGPRs held live. ----
    float2 x[T_STEPS];
#pragma unroll
    for (int t = 0; t < T_STEPS; ++t) {
        asm volatile("global_load_dwordx2 %0, %1, off"
                     : "=v"(x[t])
                     : "v"(p));
        p += N2;
    }

    // Drain all loads once. Volatile asms are ordered among themselves.
    asm volatile("s_waitcnt vmcnt(0)" ::: "memory");

    // Re-tie every value AFTER the wait: creates a data dependence so the
    // arithmetic below cannot be scheduled above the s_waitcnt.
#pragma unroll
    for (int t = 0; t < T_STEPS; ++t)
        asm volatile("" : "+v"(x[t]));

    // ---- Phase B: serial scan in registers + fire-and-forget stores ----
    float m0 = 0.f, m1 = 0.f;
#pragma unroll
    for (int t = 0; t < T_STEPS; ++t) {
        // exact reference order: mem += (x - mem) * 0.5 ; threshold 1.0
        m0 = m0 + (x[t].x - m0) * 0.5f;
        m1 = m1 + (x[t].y - m1) * 0.5f;

        float2 s;
        s.x = (m0 - 1.0f > 0.0f) ? 1.0f : 0.0f;
        s.y = (m1 - 1.0f > 0.0f) ? 1.0f : 0.0f;

        m0 = (s.x != 0.0f) ? 0.0f : m0;
        m1 = (s.y != 0.0f) ? 0.0f : m1;

        po[(size_t)t * (size_t)N2] = s;
    }
}

extern "C" void kernel_launch(void* const* d_in, const int* in_sizes, int n_in,
                              void* d_out, int out_size, void* d_ws, size_t ws_size,
                              hipStream_t stream) {
    const float2* X = (const float2*)d_in[0];
    float2* out = (float2*)d_out;

    const int total = in_sizes[0];          // B*T*N = 33554432
    const int B = total / (T_STEPS * 8192); // 128
    const int nthreads = B * N2;            // 524288

    const int block = 256;
    const int grid = (nthreads + block - 1) / block;  // 2048

    lif_fwd_kernel<<<grid, block, 0, stream>>>(X, out);
}